// Round 7
// baseline (124.405 us; speedup 1.0000x reference)
//
#include <hip/hip_runtime.h>
#include <stdint.h>

typedef _Float16 f16;
typedef __attribute__((ext_vector_type(2))) _Float16 f16x2;
typedef __attribute__((ext_vector_type(4))) _Float16 f16x4;
typedef __attribute__((ext_vector_type(8))) _Float16 f16x8;
typedef __attribute__((ext_vector_type(4))) float f32x4;

#define H0 64
#define W0 128
#define NPIX 8192   // H0*W0
#define KD 256
#define NCAT 10880  // 8192 + 2048 + 512 + 128  (= 85 * 128, exact)
#define OFF1 8192
#define OFF2 10240
#define OFF3 10752

// ---------------------------------------------------------------------------
// 1) transpose + fp32->fp16 for both fmaps: in [256][8192] -> out [8192][256]
// ---------------------------------------------------------------------------
__global__ __launch_bounds__(256) void transpose_cvt(const float* __restrict__ in0,
                                                     const float* __restrict__ in1,
                                                     f16* __restrict__ out0,
                                                     f16* __restrict__ out1) {
  const float* in = blockIdx.z ? in1 : in0;
  f16* out = blockIdx.z ? out1 : out0;
  __shared__ f16 tile[64][65];
  int t = threadIdx.x;
  int m0 = blockIdx.x * 64;
  int d0 = blockIdx.y * 64;
  int a = t & 63;
  int b = t >> 6;
#pragma unroll
  for (int i = 0; i < 16; ++i) {
    int d = b + i * 4;
    tile[a][d] = (f16)in[(size_t)(d0 + d) * NPIX + m0 + a];
  }
  __syncthreads();
#pragma unroll
  for (int i = 0; i < 16; ++i) {
    int m = b + i * 4;
    out[(size_t)(m0 + m) * KD + d0 + a] = tile[m][a];
  }
}

// ---------------------------------------------------------------------------
// 2) pooled feature rows: Bc rows [8192,10880) = 2x2/4x4/8x8 pixel means.
// ---------------------------------------------------------------------------
__global__ __launch_bounds__(256) void pool_feat(f16* __restrict__ Bc) {
  int idx = blockIdx.x * 256 + threadIdx.x;  // 86016 = 2688*32
  int dc = idx & 31;
  int r  = idx >> 5;
  int lev, y, x;
  if (r < 2048)      { lev = 1; y = r >> 6;          x = r & 63; }
  else if (r < 2560) { lev = 2; y = (r - 2048) >> 5; x = (r - 2048) & 31; }
  else               { lev = 3; y = (r - 2560) >> 4; x = (r - 2560) & 15; }
  int sz = 1 << lev;
  float acc[8] = {0, 0, 0, 0, 0, 0, 0, 0};
  for (int h = 0; h < sz; ++h)
    for (int ww = 0; ww < sz; ++ww) {
      f16x8 v = *(const f16x8*)(Bc + (size_t)((y * sz + h) * W0 + x * sz + ww) * KD + dc * 8);
#pragma unroll
      for (int e = 0; e < 8; ++e) acc[e] += (float)v[e];
    }
  float s = 1.0f / (float)(sz * sz);
  f16x8 o;
#pragma unroll
  for (int e = 0; e < 8; ++e) o[e] = (f16)(acc[e] * s);
  *(f16x8*)(Bc + (size_t)(8192 + r) * KD + dc * 8) = o;
}

// ---------------------------------------------------------------------------
// 2b) per-pixel window metadata: X0,Y0 per level packed as int8x4.
// ---------------------------------------------------------------------------
__global__ __launch_bounds__(256) void meta_prep(const float* __restrict__ coords,
                                                 int2* __restrict__ meta) {
  int m = blockIdx.x * 256 + threadIdx.x;   // 32 blocks
  float cx = coords[m];
  float cy = coords[NPIX + m];
  int mx = 0, my = 0;
#pragma unroll
  for (int lev = 0; lev < 4; ++lev) {
    float inv = 1.0f / (float)(1 << lev);
    int X0 = (int)floorf(cx * inv) - 4;     // identical expr in corr_sample
    int Y0 = (int)floorf(cy * inv) - 4;
    mx |= (X0 & 0xff) << (8 * lev);
    my |= (Y0 & 0xff) << (8 * lev);
  }
  meta[m] = make_int2(mx, my);
}

// ---------------------------------------------------------------------------
// 3) GEMM: dot[m][n] = (1/16)*sum_k A[m][k]*B[n][k], M=8192, N=10880, K=256.
//    K-loop identical to round 6 (fragment-double-buffered, 3-ring LDS).
//    EPILOGUE: instead of materializing C (178 MB, write-bound), scatter-store
//    ONLY the in-window corner values (~6.6 MB) into compact W[cidx][m],
//    cidx = lev*100 + dy*10 + dx. Each corner has exactly one writer tile.
// ---------------------------------------------------------------------------
#define GLD16(gp, lp)                                                          \
  __builtin_amdgcn_global_load_lds(                                            \
      (const __attribute__((address_space(1))) void*)(gp),                     \
      (__attribute__((address_space(3))) void*)(lp), 16, 0, 0)

__global__ __launch_bounds__(256, 2) void corr_gemm(const f16* __restrict__ A,
                                                    const f16* __restrict__ B,
                                                    const int2* __restrict__ meta,
                                                    f16* __restrict__ Wbuf) {
  extern __shared__ f16 lds[];   // 3 x 12288 f16 = 72 KB ring

  int bid = blockIdx.x;          // 2720 = 8 xcd x (4 bm x 85 bn)
  int bm = (((bid & 7) << 2) | ((bid >> 3) & 3)) << 8;
  int bn = (bid >> 5) << 7;

  int t = threadIdx.x;
  int lane = t & 63;
  int w = t >> 6;                 // wave 0..3, owns A rows [w*64, w*64+64)
  int lr = lane & 15;
  int ko = lane >> 4;

  int offA[4], offB[8];
#pragma unroll
  for (int i = 0; i < 4; ++i) {
    int row = w * 64 + i * 16 + lr;
    int line = row >> 1;
    int phys = (((row & 1) << 2) | ko) ^ (line & 7);
    offA[i] = line * 128 + phys * 16;
  }
#pragma unroll
  for (int i = 0; i < 8; ++i) {
    int row = i * 16 + lr;
    int line = row >> 1;
    int phys = (((row & 1) << 2) | ko) ^ (line & 7);
    offB[i] = line * 128 + phys * 16;
  }

  int aoff;
  {
    int c = t;
    int line = c >> 3;
    int lg = (c & 7) ^ (line & 7);
    aoff = ((line * 2 + (lg >> 2)) * KD + (lg & 3) * 8);   // f16 units
  }
  const f16* Abase = A + (size_t)bm * KD;
  const f16* Bbase = B + (size_t)bn * KD;

#define STAGE(bufi, kt)                                                        \
  do {                                                                         \
    f16* dA = lds + (bufi) * 12288;                                            \
    f16* dB = dA + 8192;                                                       \
    GLD16(Abase + aoff + (kt) * 32,                dA + t * 8);                \
    GLD16(Abase + aoff + 64 * KD + (kt) * 32,      dA + 2048 + t * 8);         \
    GLD16(Abase + aoff + 128 * KD + (kt) * 32,     dA + 4096 + t * 8);         \
    GLD16(Abase + aoff + 192 * KD + (kt) * 32,     dA + 6144 + t * 8);         \
    GLD16(Bbase + aoff + (kt) * 32,                dB + t * 8);                \
    GLD16(Bbase + aoff + 64 * KD + (kt) * 32,      dB + 2048 + t * 8);         \
  } while (0)

#define READF(s, bufi)                                                         \
  do {                                                                         \
    const char* ab = (const char*)(lds + (bufi) * 12288);                      \
    const char* bb = ab + 16384;                                               \
    _Pragma("unroll")                                                          \
    for (int i = 0; i < 4; ++i) af[s][i] = *(const f16x8*)(ab + offA[i]);      \
    _Pragma("unroll")                                                          \
    for (int i = 0; i < 8; ++i) bf[s][i] = *(const f16x8*)(bb + offB[i]);      \
  } while (0)

  f16x8 af[2][4], bf[2][8];
  f32x4 acc[4][8];
#pragma unroll
  for (int i = 0; i < 4; ++i)
#pragma unroll
    for (int j = 0; j < 8; ++j) acc[i][j] = (f32x4){0.f, 0.f, 0.f, 0.f};

  STAGE(0, 0);
  STAGE(1, 1);
  STAGE(2, 2);
  asm volatile("s_waitcnt vmcnt(6)" ::: "memory");   // stages 0,1 landed
  __builtin_amdgcn_s_barrier();
  READF(0, 0);
  asm volatile("s_waitcnt lgkmcnt(0)" ::: "memory");
  __builtin_amdgcn_sched_barrier(0);
  __builtin_amdgcn_s_barrier();                      // frags0 read by all waves

#pragma unroll
  for (int k = 0; k < 8; ++k) {
    if (k + 3 <= 7) STAGE(k % 3, k + 3);
    if (k + 1 <= 7) READF((k + 1) & 1, (k + 1) % 3);

    __builtin_amdgcn_s_setprio(1);
#pragma unroll
    for (int mi = 0; mi < 4; ++mi)
#pragma unroll
      for (int ni = 0; ni < 8; ++ni)
        acc[mi][ni] = __builtin_amdgcn_mfma_f32_16x16x32_f16(
            af[k & 1][mi], bf[k & 1][ni], acc[mi][ni], 0, 0, 0);
    __builtin_amdgcn_s_setprio(0);

    asm volatile("s_waitcnt lgkmcnt(0)" ::: "memory");
    __builtin_amdgcn_sched_barrier(0);
    if (k <= 4) asm volatile("s_waitcnt vmcnt(6)" ::: "memory");
    else        asm volatile("s_waitcnt vmcnt(0)" ::: "memory");
    __builtin_amdgcn_s_barrier();
  }

  // ---- compact-window epilogue ----
  int lev, n0, wlog;
  if (bn < OFF1)      { lev = 0; n0 = bn;        wlog = 7; }
  else if (bn < OFF2) { lev = 1; n0 = bn - OFF1; wlog = 6; }
  else if (bn < OFF3) { lev = 2; n0 = bn - OFF2; wlog = 5; }
  else                { lev = 3; n0 = bn - OFF3; wlog = 4; }
  int wmask = (1 << wlog) - 1;

  // per-lane column geometry (uniform over rows)
  int ycol[8], xcol[8];
#pragma unroll
  for (int ni = 0; ni < 8; ++ni) {
    int n = n0 + ni * 16 + lr;
    ycol[ni] = n >> wlog;
    xcol[ni] = n & wmask;
  }
  f16* wlev = Wbuf + (size_t)(lev * 100) * NPIX;

#pragma unroll
  for (int mi = 0; mi < 4; ++mi)
#pragma unroll
    for (int r2 = 0; r2 < 4; ++r2) {
      int grow = bm + w * 64 + mi * 16 + ko * 4 + r2;
      int2 mv = meta[grow];
      int X0 = (int)(signed char)((mv.x >> (lev * 8)) & 0xff);
      int Y0 = (int)(signed char)((mv.y >> (lev * 8)) & 0xff);
#pragma unroll
      for (int ni = 0; ni < 8; ++ni) {
        int dy = ycol[ni] - Y0;
        int dx = xcol[ni] - X0;
        if ((unsigned)dy < 10u && (unsigned)dx < 10u) {
          wlev[(size_t)(dy * 10 + dx) * NPIX + grow] =
              (f16)(acc[mi][ni][r2] * 0.0625f);
        }
      }
    }
#undef STAGE
#undef READF
}

// ---------------------------------------------------------------------------
// 4) bilinear sampling from compact corner buffer W[cidx][m] (coalesced).
//    grid (288,1,4): bx -> (xcd, j, m-chunk); z = level.
// ---------------------------------------------------------------------------
__global__ __launch_bounds__(256) void corr_sample(const f16* __restrict__ Wbuf,
                                                   const float* __restrict__ coords,
                                                   float* __restrict__ out) {
  int bx = blockIdx.x;            // 288 = 8 xcd * 36
  int xcd = bx & 7;
  int idx = bx >> 3;              // 0..35
  int j = idx % 9;                // window row
  int mc = xcd + 8 * (idx / 9);   // m-chunk 0..31
  int m = mc * 256 + threadIdx.x;
  int lev = blockIdx.z;
  int Hl = H0 >> lev, Wl = W0 >> lev;

  float cx = coords[m];
  float cy = coords[NPIX + m];
  float inv = 1.0f / (float)(1 << lev);
  float xb = cx * inv, yb = cy * inv;
  float fx = floorf(xb), fy = floorf(yb);
  int X0 = (int)fx - 4, Y0 = (int)fy - 4;   // matches meta_prep exactly
  float wx1 = xb - fx, wx0 = 1.0f - wx1;
  float wy1 = yb - fy, wy0 = 1.0f - wy1;

  const f16* wb = Wbuf + (size_t)(lev * 100) * NPIX + m;
  float* op = out + ((size_t)lev * 81 + (size_t)j * 9) * NPIX + m;

  float cur[10], nxt[10];
  auto loadrow = [&](float* row, int jr) {
    int y = Y0 + jr;
    bool yin = (unsigned)y < (unsigned)Hl;
#pragma unroll
    for (int i = 0; i < 10; ++i) {
      int x = X0 + i;
      bool in = yin && ((unsigned)x < (unsigned)Wl);
      row[i] = in ? (float)wb[(size_t)(jr * 10 + i) * NPIX] : 0.0f;
    }
  };
  loadrow(cur, j);
  loadrow(nxt, j + 1);
#pragma unroll
  for (int i = 0; i < 9; ++i) {
    float v = wy0 * (wx0 * cur[i] + wx1 * cur[i + 1])
            + wy1 * (wx0 * nxt[i] + wx1 * nxt[i + 1]);
    op[(size_t)i * NPIX] = v;
  }
}

// ---------------------------------------------------------------------------
extern "C" void kernel_launch(void* const* d_in, const int* in_sizes, int n_in,
                              void* d_out, int out_size, void* d_ws, size_t ws_size,
                              hipStream_t stream) {
  const float* fmap1  = (const float*)d_in[0];   // [1,256,64,128]
  const float* fmap2  = (const float*)d_in[1];
  const float* coords = (const float*)d_in[2];   // [1,2,64,128]
  float* out = (float*)d_out;                    // [1,324,64,128] fp32

  char* ws = (char*)d_ws;
  size_t offA = 0;
  size_t offB = offA + (size_t)NPIX * KD * 2;    // A: 4 MB
  size_t offW = offB + (size_t)NCAT * KD * 2;    // B: 5.44 MB
  size_t offM = offW + (size_t)400 * NPIX * 2;   // W: 6.55 MB
  size_t need = offM + (size_t)NPIX * 8;         // meta: 64 KB => ~16.1 MB
  if (ws_size < need) return;

  f16*  A    = (f16*)(ws + offA);
  f16*  Bc   = (f16*)(ws + offB);
  f16*  Wbuf = (f16*)(ws + offW);
  int2* meta = (int2*)(ws + offM);

  const int LDS_BYTES = 3 * 12288 * 2;  // 72 KB
  hipFuncSetAttribute(reinterpret_cast<const void*>(corr_gemm),
                      hipFuncAttributeMaxDynamicSharedMemorySize, LDS_BYTES);

  transpose_cvt<<<dim3(128, 4, 2), 256, 0, stream>>>(fmap1, fmap2, A, Bc);
  pool_feat<<<336, 256, 0, stream>>>(Bc);
  meta_prep<<<32, 256, 0, stream>>>(coords, meta);
  corr_gemm<<<2720, 256, LDS_BYTES, stream>>>(A, Bc, meta, Wbuf);
  corr_sample<<<dim3(288, 1, 4), 256, 0, stream>>>(Wbuf, coords, out);
}